// Round 12
// baseline (583.122 us; speedup 1.0000x reference)
//
#include <hip/hip_runtime.h>
#include <hip/hip_bf16.h>
#include <cstdint>

#define HIDDEN 4096
#define NQ 32
#define NKV 8
#define HD 128
#define BB 4
#define SS 1024
#define NTOK (BB*SS)
#define NQKV 6144

typedef __bf16 bf16x8 __attribute__((ext_vector_type(8)));
typedef float f32x4 __attribute__((ext_vector_type(4)));
typedef unsigned short u16;
typedef unsigned int u32;

__device__ __forceinline__ void gload_lds16(const void* g, void* l) {
  __builtin_amdgcn_global_load_lds((const __attribute__((address_space(1))) u32*)g,
                                   (__attribute__((address_space(3))) u32*)l, 16, 0, 0);
}

__device__ __forceinline__ u16 f2bf(float f) {
  u32 x = __float_as_uint(f);
  u32 r = x + 0x7fffu + ((x >> 16) & 1u);
  return (u16)(r >> 16);
}
__device__ __forceinline__ float bf2f(u16 x) {
  u32 v = ((u32)x) << 16;
  return __uint_as_float(v);
}

// ---------------- cast f32 -> bf16 (16B/lane writes) ----------------
__global__ void cast_f32_bf16_k(const float4* __restrict__ in, ushort4* __restrict__ out, int n8)
{
  for (int i = blockIdx.x*blockDim.x + threadIdx.x; i < n8; i += gridDim.x*blockDim.x) {
    float4 a = in[2*i], b = in[2*i+1];
    ushort4 o0, o1;
    o0.x = f2bf(a.x); o0.y = f2bf(a.y); o0.z = f2bf(a.z); o0.w = f2bf(a.w);
    o1.x = f2bf(b.x); o1.y = f2bf(b.y); o1.z = f2bf(b.z); o1.w = f2bf(b.w);
    out[2*i]   = o0;
    out[2*i+1] = o1;
  }
}

// ---------------- transpose + cast: in[K][N] f32 -> out[N][K] bf16, 64x64 tiles ----------------
__global__ __launch_bounds__(256) void transpose_cast64(const float* __restrict__ in,
                                                        u16* __restrict__ out, int K, int N)
{
  __shared__ float tile[64][65];
  const int n0 = blockIdx.x*64, k0 = blockIdx.y*64;
  const int tid = threadIdx.x;
  {
    const int tx = tid & 15, ty = tid >> 4;
    #pragma unroll
    for (int i=0;i<4;i++) {
      const int k = ty + i*16;
      float4 v = *(const float4*)&in[(size_t)(k0+k)*N + n0 + tx*4];
      tile[k][tx*4+0]=v.x; tile[k][tx*4+1]=v.y; tile[k][tx*4+2]=v.z; tile[k][tx*4+3]=v.w;
    }
  }
  __syncthreads();
  {
    const int kg = tid & 7;
    const int nb = tid >> 3;
    #pragma unroll
    for (int half=0; half<2; ++half) {
      const int n = nb + half*32;
      u16 tmp[8];
      #pragma unroll
      for (int j=0;j<8;j++) tmp[j] = f2bf(tile[kg*8+j][n]);
      *(bf16x8*)&out[(size_t)(n0+n)*K + k0 + kg*8] = *(bf16x8*)tmp;
    }
  }
}

// ---------------- rope cos/sin table ----------------
__global__ void rope_tab_k(const int* __restrict__ pos, float2* __restrict__ tab)
{
  int i = blockIdx.x*256 + threadIdx.x;
  if (i >= NTOK*64) return;
  int t = i >> 6, j = i & 63;
  float p = (float)pos[t];
  const float l2t = 19.931568569324174f;   // log2(1e6)
  float inv = exp2f(-(float)j * (l2t/64.0f));
  float f = p * inv;
  tab[i] = make_float2(cosf(f), sinf(f));
}

// ---------------- GEMM: C[M][N] = A[M][K] * Bt[N][K]^T  (bf16 in, f32 acc) ----------------
// 128x128 tile + T3-minimum 2-phase: double-buffered LDS, STAGE(t+1) issued BEFORE
// compute(t), ONE vmcnt(0)+barrier per tile (drain covered by ~1700cy of compute).
// MODE: 0 = f32 out, 1 = bf16 out, 2 = bf16 + fused per-head RMSNorm+RoPE (n-tile == head).
template<int MODE>
__global__ __launch_bounds__(256, 2) void gemm_bt(const u16* __restrict__ A,
                                                  const u16* __restrict__ Bt,
                                                  void* __restrict__ Cv,
                                                  int M, int N, int K,
                                                  const float* __restrict__ qsc,
                                                  const float* __restrict__ ksc,
                                                  const float2* __restrict__ tab)
{
  __shared__ u16 lA[2][128*64];
  __shared__ u16 lB[2][128*64];
  __shared__ float rowsum[128][2];
  const int m0 = blockIdx.y*128, n0 = blockIdx.x*128;
  const int tid = threadIdx.x;
  const int w = tid >> 6, l = tid & 63;
  const int wr = w >> 1, wc = w & 1;
  const int cl = l & 15, g4 = l >> 4;
  const int lr = l >> 3, gd = l & 7;
  f32x4 acc[4][4] = {};
  const int nt = K >> 6;

#define STG(buf, kt) do { \
    const size_t ko = (size_t)(kt)*64; \
    _Pragma("unroll") for (int c2 = 0; c2 < 4; ++c2) { \
      int r = w*32 + c2*8 + lr; \
      int gs = gd ^ (r & 7); \
      gload_lds16(A  + (size_t)(m0+r)*K + ko + gs*8, &lA[buf][(w*32 + c2*8)*64]); \
      gload_lds16(Bt + (size_t)(n0+r)*K + ko + gs*8, &lB[buf][(w*32 + c2*8)*64]); \
    } \
  } while(0)

  // prologue: stage tile 0, drain, barrier
  STG(0, 0);
  asm volatile("s_waitcnt vmcnt(0)" ::: "memory");
  __builtin_amdgcn_s_barrier();

  int cur = 0;
  for (int t = 0; t < nt; ++t) {
    // issue next tile's staging FIRST (latency hides under compute below)
    if (t+1 < nt) STG(cur^1, t+1);
    // compute tile t from buf[cur] (compiler interleaves ds_read/MFMA, lgkm-drained by MFMA deps)
    #pragma unroll
    for (int kk = 0; kk < 2; ++kk) {
      bf16x8 af[4], bfr[4];
      #pragma unroll
      for (int i=0;i<4;i++) {
        int ra = wr*64 + i*16 + cl;
        af[i]  = *(const bf16x8*)&lA[cur][ra*64 + ((kk*4+g4) ^ (ra&7))*8];
        int rb = wc*64 + i*16 + cl;
        bfr[i] = *(const bf16x8*)&lB[cur][rb*64 + ((kk*4+g4) ^ (rb&7))*8];
      }
      #pragma unroll
      for (int i=0;i<4;i++)
        #pragma unroll
        for (int j=0;j<4;j++)
          acc[i][j] = __builtin_amdgcn_mfma_f32_16x16x32_bf16(af[i], bfr[j], acc[i][j], 0,0,0);
    }
    // staged loads have had the whole compute to land -> near-free drain
    asm volatile("s_waitcnt vmcnt(0)" ::: "memory");
    __builtin_amdgcn_s_barrier();
    cur ^= 1;
  }
#undef STG

  if (MODE == 2 && n0 < 5120) {
    // ---- fused RMSNorm + RoPE: this n-tile is exactly one Q or K head ----
    const float* sc = (n0 < 4096) ? qsc : ksc;
    #pragma unroll
    for (int i=0;i<4;i++)
      #pragma unroll
      for (int rg=0;rg<4;rg++) {
        float ss = 0.f;
        #pragma unroll
        for (int j=0;j<4;j++) ss += acc[i][j][rg]*acc[i][j][rg];
        ss += __shfl_xor(ss,1); ss += __shfl_xor(ss,2);
        ss += __shfl_xor(ss,4); ss += __shfl_xor(ss,8);
        if (cl == 0) rowsum[wr*64 + i*16 + g4*4 + rg][wc] = ss;
      }
    __syncthreads();
    #pragma unroll
    for (int i=0;i<4;i++)
      #pragma unroll
      for (int rg=0;rg<4;rg++) {
        const int lrow = wr*64 + i*16 + g4*4 + rg;
        const float rn = rsqrtf((rowsum[lrow][0] + rowsum[lrow][1])*(1.0f/128.0f) + 1e-6f);
        const int token = m0 + lrow;
        #pragma unroll
        for (int j=0;j<4;j++) {
          const int cih = wc*64 + j*16 + cl;          // col within head
          float y  = acc[i][j][rg] * rn * sc[cih];
          float py = __shfl_xor(y, 1);                 // rope partner (col ^ 1)
          float2 cs = tab[token*64 + (cih >> 1)];
          float o = (cl & 1) ? fmaf(y, cs.x,  py*cs.y)
                             : fmaf(y, cs.x, -py*cs.y);
          ((u16*)Cv)[(size_t)token*N + n0 + cih] = f2bf(o);
        }
      }
  } else {
    #pragma unroll
    for (int i=0;i<4;i++)
      #pragma unroll
      for (int rg=0;rg<4;rg++) {
        size_t row = m0 + wr*64 + i*16 + g4*4 + rg;
        #pragma unroll
        for (int j=0;j<4;j++) {
          size_t col = n0 + wc*64 + j*16 + cl;
          if (MODE != 0) ((u16*)Cv)[row*N + col] = f2bf(acc[i][j][rg]);
          else           ((float*)Cv)[row*N + col] = acc[i][j][rg];
        }
      }
  }
}

// ---------------- V transpose: qkv V-slice -> vt[(b*8+kvh)*128 + d][S] ----------------
__global__ __launch_bounds__(256) void v_transpose(const u16* __restrict__ qkv,
                                                   u16* __restrict__ vt)
{
  __shared__ u16 tile[32][136];            // [s][d], padded
  const int s0 = blockIdx.x*32;
  const int z  = blockIdx.y;               // b*8 + kvh
  const int b = z >> 3, kvh = z & 7;
  const int tid = threadIdx.x;
  const int tr = tid >> 4, ln = tid & 15;
  const size_t base = ((size_t)b*SS)*NQKV + 5120 + (size_t)kvh*HD;
  #pragma unroll
  for (int i=0;i<2;i++) {
    int srow = tr + i*16;
    *(bf16x8*)&tile[srow][ln*8] =
        *(const bf16x8*)&qkv[base + (size_t)(s0+srow)*NQKV + ln*8];
  }
  __syncthreads();
  const int dr = tid >> 1, sh = (tid & 1)*16;
  u16 tmp[16];
  #pragma unroll
  for (int j=0;j<16;j++) tmp[j] = tile[sh+j][dr];
  u16* o = vt + ((size_t)z*HD + dr)*SS + s0 + sh;
  *(bf16x8*)o       = *(const bf16x8*)&tmp[0];
  *(bf16x8*)(o + 8) = *(const bf16x8*)&tmp[8];
}

// ---------------- causal GQA flash attention v3 ----------------
// Double-buffered LDS K/V staging via global_load_lds (async, shared by 4 waves),
// 2-phase pipeline: STAGE(next) || compute(cur), one barrier per chunk.
// Pairing: block qp handles q-tiles {qp, 15-qp} (uniform 17 chunks).
__global__ __launch_bounds__(256, 2) void attn_fwd(const u16* __restrict__ qkv,
                                                   const u16* __restrict__ vt,
                                                   u16* __restrict__ out)
{
  __shared__ u16 Kb[2][64*128];            // K tile [kv][d], granule^=(kv&15)
  __shared__ u16 Vb[2][128*64];            // V^T tile [d][kv], granule^=(d&7)
  __shared__ u16 Pl[4][16*64];             // per-wave P [q][kv], granule^=(q&7)
  const int qp = blockIdx.x, h = blockIdx.y, b = blockIdx.z;
  const int kvh = h >> 2;
  const int tid = threadIdx.x, w = tid >> 6, l = tid & 63;
  const int cl = l & 15, g4 = l >> 4;
  const float csc = 1.4426950408889634f * 0.08838834764831845f;  // log2e / sqrt(128)
  const size_t kbase = ((size_t)b*SS)*NQKV + 4096 + (size_t)kvh*HD;
  const size_t vbase = ((size_t)b*8 + (size_t)kvh)*HD*SS;
  u16* Pw = &Pl[w][0];

  // staging lane roles
  const int kr_l = l >> 4, kg_l = l & 15;   // K: 4 rows x 16 granules / instr
  const int vr_l = l >> 3, vg_l = l & 7;    // V: 8 rows x 8 granules / instr

  #pragma unroll
  for (int t = 0; t < 2; ++t) {
    const int qt = t ? (15 - qp) : qp;
    const int q0 = qt*64;

    bf16x8 qf[4];
    const size_t qrow = ((size_t)b*SS + q0 + w*16 + cl)*NQKV + h*HD;
    #pragma unroll
    for (int kk=0;kk<4;kk++) qf[kk] = *(const bf16x8*)&qkv[qrow + kk*32 + g4*8];

    f32x4 O[8] = {};
    float mrow[4] = {-INFINITY,-INFINITY,-INFINITY,-INFINITY};
    float srow[4] = {0.f,0.f,0.f,0.f};

    const int nch = qt + 1;

    // ---- prologue: stage chunk 0 ----
    #pragma unroll
    for (int i=0;i<4;i++) {
      int inst = w*4 + i;
      int r = inst*4 + kr_l;
      int g = kg_l ^ (r & 15);
      gload_lds16(qkv + kbase + (size_t)r*NQKV + g*8, &Kb[0][inst*512]);
      int d = inst*8 + vr_l;
      int gv = vg_l ^ (d & 7);
      gload_lds16(vt + vbase + (size_t)d*SS + gv*8, &Vb[0][inst*512]);
    }
    __syncthreads();
    int cur = 0;

    for (int ch = 0; ch < nch; ++ch) {
      const int kv0 = ch*64;
      // ---- stage next chunk (async) ----
      if (ch + 1 < nch) {
        const size_t knext = kbase + (size_t)(kv0+64)*NQKV;
        const size_t vnext = vbase + (size_t)(kv0+64);
        u16* Kn = &Kb[cur^1][0];
        u16* Vn = &Vb[cur^1][0];
        #pragma unroll
        for (int i=0;i<4;i++) {
          int inst = w*4 + i;
          int r = inst*4 + kr_l;
          int g = kg_l ^ (r & 15);
          gload_lds16(qkv + knext + (size_t)r*NQKV + g*8, Kn + inst*512);
          int d = inst*8 + vr_l;
          int gv = vg_l ^ (d & 7);
          gload_lds16(vt + vnext + (size_t)d*SS + gv*8, Vn + inst*512);
        }
      }
      const u16* Kt  = &Kb[cur][0];
      const u16* Vtl = &Vb[cur][0];
      // ---- QK^T from LDS ----
      f32x4 s[4] = {};
      #pragma unroll
      for (int cc=0;cc<4;cc++) {
        const int kro = (cc*16+cl)*128;
        #pragma unroll
        for (int kk=0;kk<4;kk++) {
          bf16x8 kf = *(const bf16x8*)&Kt[kro + (((kk*4+g4) ^ cl))*8];
          s[cc] = __builtin_amdgcn_mfma_f32_16x16x32_bf16(qf[kk], kf, s[cc], 0,0,0);
        }
      }
      // ---- online softmax (16-lane row groups) ----
      float alpha[4];
      #pragma unroll
      for (int rg=0; rg<4; ++rg) {
        const int qr = q0 + w*16 + g4*4 + rg;
        float sv[4];
        #pragma unroll
        for (int cc=0;cc<4;cc++) {
          sv[cc] = s[cc][rg]*csc;
          if (kv0 + cc*16 + cl > qr) sv[cc] = -INFINITY;
        }
        float mx = fmaxf(fmaxf(sv[0],sv[1]), fmaxf(sv[2],sv[3]));
        mx = fmaxf(mx, __shfl_xor(mx,1));
        mx = fmaxf(mx, __shfl_xor(mx,2));
        mx = fmaxf(mx, __shfl_xor(mx,4));
        mx = fmaxf(mx, __shfl_xor(mx,8));
        float mn = fmaxf(mrow[rg], mx);
        float al = exp2f(mrow[rg] - mn);
        mrow[rg] = mn;
        float p0 = exp2f(sv[0]-mn), p1 = exp2f(sv[1]-mn);
        float p2 = exp2f(sv[2]-mn), p3 = exp2f(sv[3]-mn);
        float ps = (p0+p1)+(p2+p3);
        ps += __shfl_xor(ps,1); ps += __shfl_xor(ps,2);
        ps += __shfl_xor(ps,4); ps += __shfl_xor(ps,8);
        srow[rg] = srow[rg]*al + ps;
        alpha[rg] = al;
        const int r = g4*4+rg;
        const int rs = r*64, rx = r&7;
        float pv[4] = {p0,p1,p2,p3};
        #pragma unroll
        for (int cc=0;cc<4;cc++) {
          int c = cc*16+cl;
          Pw[rs + (((c>>3) ^ rx))*8 + (c&7)] = f2bf(pv[cc]);
        }
      }
      // ---- rescale O, PV from LDS ----
      #pragma unroll
      for (int dc=0;dc<8;dc++)
        #pragma unroll
        for (int rg=0;rg<4;rg++) O[dc][rg] *= alpha[rg];
      #pragma unroll
      for (int cc2=0;cc2<2;cc2++) {
        bf16x8 pf = *(const bf16x8*)&Pw[cl*64 + (((cc2*4+g4) ^ (cl&7)))*8];
        #pragma unroll
        for (int dc=0;dc<8;dc++) {
          bf16x8 vf = *(const bf16x8*)&Vtl[(dc*16+cl)*64 + (((cc2*4+g4) ^ (cl&7)))*8];
          O[dc] = __builtin_amdgcn_mfma_f32_16x16x32_bf16(pf, vf, O[dc], 0,0,0);
        }
      }
      __syncthreads();   // drains staged loads (compiler emits vmcnt(0)) + all waves done with cur
      cur ^= 1;
    }
    // ---- epilogue for this tile ----
    #pragma unroll
    for (int rg=0;rg<4;rg++) {
      float inv = 1.0f / srow[rg];
      size_t ob = ((size_t)b*SS + q0 + w*16 + g4*4 + rg)*4096 + (size_t)h*HD;
      #pragma unroll
      for (int dc=0;dc<8;dc++)
        out[ob + dc*16 + cl] = f2bf(O[dc][rg]*inv);
    }
  }
}

// ---------------- host launcher ----------------
extern "C" void kernel_launch(void* const* d_in, const int* in_sizes, int n_in,
                              void* d_out, int out_size, void* d_ws, size_t ws_size,
                              hipStream_t stream)
{
  const float* hid = (const float*)d_in[0];
  const int*   pos = (const int*)d_in[1];
  const float* wq  = (const float*)d_in[2];
  const float* wk  = (const float*)d_in[3];
  const float* wv  = (const float*)d_in[4];
  const float* wo  = (const float*)d_in[5];
  const float* qsc = (const float*)d_in[6];
  const float* ksc = (const float*)d_in[7];

  char* ws = (char*)d_ws;
  size_t off = 0;
  auto alloc = [&](size_t b) -> char* {
    char* p = ws + off;
    off = (off + b + 255) & ~(size_t)255;
    return p;
  };
  u16*    h_bf   = (u16*)   alloc((size_t)NTOK*HIDDEN*2);
  u16*    wqkv_t = (u16*)   alloc((size_t)NQKV*HIDDEN*2);
  u16*    wo_t   = (u16*)   alloc((size_t)HIDDEN*HIDDEN*2);
  u16*    qkv    = (u16*)   alloc((size_t)NTOK*NQKV*2);
  u16*    attn_o = (u16*)   alloc((size_t)NTOK*HIDDEN*2);
  u16*    vtb    = (u16*)   alloc((size_t)BB*NKV*HD*SS*2);
  float2* tab    = (float2*)alloc((size_t)NTOK*64*sizeof(float2));

  cast_f32_bf16_k<<<2048, 256, 0, stream>>>((const float4*)hid, (ushort4*)h_bf, NTOK*HIDDEN/8);
  transpose_cast64<<<dim3(HIDDEN/64, HIDDEN/64), 256, 0, stream>>>(wq, wqkv_t, HIDDEN, HIDDEN);
  transpose_cast64<<<dim3(1024/64,  HIDDEN/64), 256, 0, stream>>>(wk, wqkv_t + (size_t)4096*HIDDEN, HIDDEN, 1024);
  transpose_cast64<<<dim3(1024/64,  HIDDEN/64), 256, 0, stream>>>(wv, wqkv_t + (size_t)5120*HIDDEN, HIDDEN, 1024);
  transpose_cast64<<<dim3(HIDDEN/64, HIDDEN/64), 256, 0, stream>>>(wo, wo_t, HIDDEN, HIDDEN);
  rope_tab_k<<<NTOK*64/256, 256, 0, stream>>>(pos, tab);

  // QKV GEMM with fused RMSNorm+RoPE epilogue (n-tile == head)
  gemm_bt<2><<<dim3(NQKV/128, NTOK/128), 256, 0, stream>>>(h_bf, wqkv_t, qkv, NTOK, NQKV, HIDDEN, qsc, ksc, tab);
  v_transpose<<<dim3(SS/32, BB*NKV), 256, 0, stream>>>(qkv, vtb);
  attn_fwd<<<dim3(8, NQ, BB), 256, 0, stream>>>(qkv, vtb, attn_o);
  gemm_bt<0><<<dim3(HIDDEN/128, NTOK/128), 256, 0, stream>>>(attn_o, wo_t, d_out, NTOK, HIDDEN, HIDDEN, nullptr, nullptr, nullptr);
}

// Round 13
// 512.479 us; speedup vs baseline: 1.1378x; 1.1378x over previous
//
#include <hip/hip_runtime.h>
#include <hip/hip_bf16.h>
#include <cstdint>

#define HIDDEN 4096
#define NQ 32
#define NKV 8
#define HD 128
#define BB 4
#define SS 1024
#define NTOK (BB*SS)
#define NQKV 6144

typedef __bf16 bf16x8 __attribute__((ext_vector_type(8)));
typedef float f32x4 __attribute__((ext_vector_type(4)));
typedef unsigned short u16;
typedef unsigned int u32;

__device__ __forceinline__ void gload_lds16(const void* g, void* l) {
  __builtin_amdgcn_global_load_lds((const __attribute__((address_space(1))) u32*)g,
                                   (__attribute__((address_space(3))) u32*)l, 16, 0, 0);
}

__device__ __forceinline__ u16 f2bf(float f) {
  u32 x = __float_as_uint(f);
  u32 r = x + 0x7fffu + ((x >> 16) & 1u);
  return (u16)(r >> 16);
}
__device__ __forceinline__ float bf2f(u16 x) {
  u32 v = ((u32)x) << 16;
  return __uint_as_float(v);
}

// ---------------- cast f32 -> bf16 (16B/lane writes) ----------------
__global__ void cast_f32_bf16_k(const float4* __restrict__ in, ushort4* __restrict__ out, int n8)
{
  for (int i = blockIdx.x*blockDim.x + threadIdx.x; i < n8; i += gridDim.x*blockDim.x) {
    float4 a = in[2*i], b = in[2*i+1];
    ushort4 o0, o1;
    o0.x = f2bf(a.x); o0.y = f2bf(a.y); o0.z = f2bf(a.z); o0.w = f2bf(a.w);
    o1.x = f2bf(b.x); o1.y = f2bf(b.y); o1.z = f2bf(b.z); o1.w = f2bf(b.w);
    out[2*i]   = o0;
    out[2*i+1] = o1;
  }
}

// ---------------- transpose + cast: in[K][N] f32 -> out[N][K] bf16, 64x64 tiles ----------------
__global__ __launch_bounds__(256) void transpose_cast64(const float* __restrict__ in,
                                                        u16* __restrict__ out, int K, int N)
{
  __shared__ float tile[64][65];
  const int n0 = blockIdx.x*64, k0 = blockIdx.y*64;
  const int tid = threadIdx.x;
  {
    const int tx = tid & 15, ty = tid >> 4;
    #pragma unroll
    for (int i=0;i<4;i++) {
      const int k = ty + i*16;
      float4 v = *(const float4*)&in[(size_t)(k0+k)*N + n0 + tx*4];
      tile[k][tx*4+0]=v.x; tile[k][tx*4+1]=v.y; tile[k][tx*4+2]=v.z; tile[k][tx*4+3]=v.w;
    }
  }
  __syncthreads();
  {
    const int kg = tid & 7;
    const int nb = tid >> 3;
    #pragma unroll
    for (int half=0; half<2; ++half) {
      const int n = nb + half*32;
      u16 tmp[8];
      #pragma unroll
      for (int j=0;j<8;j++) tmp[j] = f2bf(tile[kg*8+j][n]);
      *(bf16x8*)&out[(size_t)(n0+n)*K + k0 + kg*8] = *(bf16x8*)tmp;
    }
  }
}

// ---------------- rope cos/sin table ----------------
__global__ void rope_tab_k(const int* __restrict__ pos, float2* __restrict__ tab)
{
  int i = blockIdx.x*256 + threadIdx.x;
  if (i >= NTOK*64) return;
  int t = i >> 6, j = i & 63;
  float p = (float)pos[t];
  const float l2t = 19.931568569324174f;   // log2(1e6)
  float inv = exp2f(-(float)j * (l2t/64.0f));
  float f = p * inv;
  tab[i] = make_float2(cosf(f), sinf(f));
}

// ---------------- GEMM: C[M][N] = A[M][K] * Bt[N][K]^T  (bf16 in, f32 acc) ----------------
// Proven 128x128 structure (round 4). MODE: 0 = f32 out, 1 = bf16 out,
// 2 = bf16 out + fused per-head RMSNorm+RoPE for Q/K head tiles (n-tile == one head).
template<int MODE>
__global__ __launch_bounds__(256, 2) void gemm_bt(const u16* __restrict__ A,
                                                  const u16* __restrict__ Bt,
                                                  void* __restrict__ Cv,
                                                  int M, int N, int K,
                                                  const float* __restrict__ qsc,
                                                  const float* __restrict__ ksc,
                                                  const float2* __restrict__ tab)
{
  __shared__ u16 lA[128*64];
  __shared__ u16 lB[128*64];
  __shared__ float rowsum[128][2];
  const int m0 = blockIdx.y*128, n0 = blockIdx.x*128;
  const int tid = threadIdx.x;
  const int w = tid >> 6, l = tid & 63;
  const int wr = w >> 1, wc = w & 1;
  const int cl = l & 15, g4 = l >> 4;
  const int lr = l >> 3, gd = l & 7;
  f32x4 acc[4][4] = {};

  for (int k0 = 0; k0 < K; k0 += 64) {
    #pragma unroll
    for (int c2 = 0; c2 < 4; ++c2) {
      int r = w*32 + c2*8 + lr;
      int gs = gd ^ (r & 7);
      gload_lds16(A  + (size_t)(m0+r)*K + k0 + gs*8, &lA[(w*32 + c2*8)*64]);
      gload_lds16(Bt + (size_t)(n0+r)*K + k0 + gs*8, &lB[(w*32 + c2*8)*64]);
    }
    __syncthreads();
    #pragma unroll
    for (int kk = 0; kk < 2; ++kk) {
      bf16x8 af[4], bfr[4];
      #pragma unroll
      for (int i=0;i<4;i++) {
        int ra = wr*64 + i*16 + cl;
        af[i]  = *(const bf16x8*)&lA[ra*64 + ((kk*4+g4) ^ (ra&7))*8];
        int rb = wc*64 + i*16 + cl;
        bfr[i] = *(const bf16x8*)&lB[rb*64 + ((kk*4+g4) ^ (rb&7))*8];
      }
      #pragma unroll
      for (int i=0;i<4;i++)
        #pragma unroll
        for (int j=0;j<4;j++)
          acc[i][j] = __builtin_amdgcn_mfma_f32_16x16x32_bf16(af[i], bfr[j], acc[i][j], 0,0,0);
    }
    __syncthreads();
  }

  if (MODE == 2 && n0 < 5120) {
    // ---- fused RMSNorm + RoPE: this n-tile is exactly one Q or K head ----
    const float* sc = (n0 < 4096) ? qsc : ksc;
    #pragma unroll
    for (int i=0;i<4;i++)
      #pragma unroll
      for (int rg=0;rg<4;rg++) {
        float ss = 0.f;
        #pragma unroll
        for (int j=0;j<4;j++) ss += acc[i][j][rg]*acc[i][j][rg];
        ss += __shfl_xor(ss,1); ss += __shfl_xor(ss,2);
        ss += __shfl_xor(ss,4); ss += __shfl_xor(ss,8);
        if (cl == 0) rowsum[wr*64 + i*16 + g4*4 + rg][wc] = ss;
      }
    __syncthreads();
    #pragma unroll
    for (int i=0;i<4;i++)
      #pragma unroll
      for (int rg=0;rg<4;rg++) {
        const int lrow = wr*64 + i*16 + g4*4 + rg;
        const float rn = rsqrtf((rowsum[lrow][0] + rowsum[lrow][1])*(1.0f/128.0f) + 1e-6f);
        const int token = m0 + lrow;
        #pragma unroll
        for (int j=0;j<4;j++) {
          const int cih = wc*64 + j*16 + cl;          // col within head
          float y  = acc[i][j][rg] * rn * sc[cih];
          float py = __shfl_xor(y, 1);                 // rope partner (col ^ 1)
          float2 cs = tab[token*64 + (cih >> 1)];
          float o = (cl & 1) ? fmaf(y, cs.x,  py*cs.y)
                             : fmaf(y, cs.x, -py*cs.y);
          ((u16*)Cv)[(size_t)token*N + n0 + cih] = f2bf(o);
        }
      }
  } else {
    #pragma unroll
    for (int i=0;i<4;i++)
      #pragma unroll
      for (int rg=0;rg<4;rg++) {
        size_t row = m0 + wr*64 + i*16 + g4*4 + rg;
        #pragma unroll
        for (int j=0;j<4;j++) {
          size_t col = n0 + wc*64 + j*16 + cl;
          if (MODE != 0) ((u16*)Cv)[row*N + col] = f2bf(acc[i][j][rg]);
          else           ((float*)Cv)[row*N + col] = acc[i][j][rg];
        }
      }
  }
}

// ---------------- V transpose: qkv V-slice -> vt[(b*8+kvh)*128 + d][S] ----------------
__global__ __launch_bounds__(256) void v_transpose(const u16* __restrict__ qkv,
                                                   u16* __restrict__ vt)
{
  __shared__ u16 tile[32][136];            // [s][d], padded
  const int s0 = blockIdx.x*32;
  const int z  = blockIdx.y;               // b*8 + kvh
  const int b = z >> 3, kvh = z & 7;
  const int tid = threadIdx.x;
  const int tr = tid >> 4, ln = tid & 15;
  const size_t base = ((size_t)b*SS)*NQKV + 5120 + (size_t)kvh*HD;
  #pragma unroll
  for (int i=0;i<2;i++) {
    int srow = tr + i*16;
    *(bf16x8*)&tile[srow][ln*8] =
        *(const bf16x8*)&qkv[base + (size_t)(s0+srow)*NQKV + ln*8];
  }
  __syncthreads();
  const int dr = tid >> 1, sh = (tid & 1)*16;
  u16 tmp[16];
  #pragma unroll
  for (int j=0;j<16;j++) tmp[j] = tile[sh+j][dr];
  u16* o = vt + ((size_t)z*HD + dr)*SS + s0 + sh;
  *(bf16x8*)o       = *(const bf16x8*)&tmp[0];
  *(bf16x8*)(o + 8) = *(const bf16x8*)&tmp[8];
}

// ---------------- causal GQA flash attention v3 ----------------
// Double-buffered LDS K/V staging via global_load_lds (async, shared by 4 waves),
// 2-phase pipeline: STAGE(next) || compute(cur), one barrier per chunk.
// Pairing: block qp handles q-tiles {qp, 15-qp} (uniform 17 chunks).
__global__ __launch_bounds__(256, 2) void attn_fwd(const u16* __restrict__ qkv,
                                                   const u16* __restrict__ vt,
                                                   u16* __restrict__ out)
{
  __shared__ u16 Kb[2][64*128];            // K tile [kv][d], granule^=(kv&15)
  __shared__ u16 Vb[2][128*64];            // V^T tile [d][kv], granule^=(d&7)
  __shared__ u16 Pl[4][16*64];             // per-wave P [q][kv], granule^=(q&7)
  const int qp = blockIdx.x, h = blockIdx.y, b = blockIdx.z;
  const int kvh = h >> 2;
  const int tid = threadIdx.x, w = tid >> 6, l = tid & 63;
  const int cl = l & 15, g4 = l >> 4;
  const float csc = 1.4426950408889634f * 0.08838834764831845f;  // log2e / sqrt(128)
  const size_t kbase = ((size_t)b*SS)*NQKV + 4096 + (size_t)kvh*HD;
  const size_t vbase = ((size_t)b*8 + (size_t)kvh)*HD*SS;
  u16* Pw = &Pl[w][0];

  // staging lane roles
  const int kr_l = l >> 4, kg_l = l & 15;   // K: 4 rows x 16 granules / instr
  const int vr_l = l >> 3, vg_l = l & 7;    // V: 8 rows x 8 granules / instr

  #pragma unroll
  for (int t = 0; t < 2; ++t) {
    const int qt = t ? (15 - qp) : qp;
    const int q0 = qt*64;

    bf16x8 qf[4];
    const size_t qrow = ((size_t)b*SS + q0 + w*16 + cl)*NQKV + h*HD;
    #pragma unroll
    for (int kk=0;kk<4;kk++) qf[kk] = *(const bf16x8*)&qkv[qrow + kk*32 + g4*8];

    f32x4 O[8] = {};
    float mrow[4] = {-INFINITY,-INFINITY,-INFINITY,-INFINITY};
    float srow[4] = {0.f,0.f,0.f,0.f};

    const int nch = qt + 1;

    // ---- prologue: stage chunk 0 ----
    #pragma unroll
    for (int i=0;i<4;i++) {
      int inst = w*4 + i;
      int r = inst*4 + kr_l;
      int g = kg_l ^ (r & 15);
      gload_lds16(qkv + kbase + (size_t)r*NQKV + g*8, &Kb[0][inst*512]);
      int d = inst*8 + vr_l;
      int gv = vg_l ^ (d & 7);
      gload_lds16(vt + vbase + (size_t)d*SS + gv*8, &Vb[0][inst*512]);
    }
    __syncthreads();
    int cur = 0;

    for (int ch = 0; ch < nch; ++ch) {
      const int kv0 = ch*64;
      // ---- stage next chunk (async) ----
      if (ch + 1 < nch) {
        const size_t knext = kbase + (size_t)(kv0+64)*NQKV;
        const size_t vnext = vbase + (size_t)(kv0+64);
        u16* Kn = &Kb[cur^1][0];
        u16* Vn = &Vb[cur^1][0];
        #pragma unroll
        for (int i=0;i<4;i++) {
          int inst = w*4 + i;
          int r = inst*4 + kr_l;
          int g = kg_l ^ (r & 15);
          gload_lds16(qkv + knext + (size_t)r*NQKV + g*8, Kn + inst*512);
          int d = inst*8 + vr_l;
          int gv = vg_l ^ (d & 7);
          gload_lds16(vt + vnext + (size_t)d*SS + gv*8, Vn + inst*512);
        }
      }
      const u16* Kt  = &Kb[cur][0];
      const u16* Vtl = &Vb[cur][0];
      // ---- QK^T from LDS ----
      f32x4 s[4] = {};
      #pragma unroll
      for (int cc=0;cc<4;cc++) {
        const int kro = (cc*16+cl)*128;
        #pragma unroll
        for (int kk=0;kk<4;kk++) {
          bf16x8 kf = *(const bf16x8*)&Kt[kro + (((kk*4+g4) ^ cl))*8];
          s[cc] = __builtin_amdgcn_mfma_f32_16x16x32_bf16(qf[kk], kf, s[cc], 0,0,0);
        }
      }
      // ---- online softmax (16-lane row groups) ----
      float alpha[4];
      #pragma unroll
      for (int rg=0; rg<4; ++rg) {
        const int qr = q0 + w*16 + g4*4 + rg;
        float sv[4];
        #pragma unroll
        for (int cc=0;cc<4;cc++) {
          sv[cc] = s[cc][rg]*csc;
          if (kv0 + cc*16 + cl > qr) sv[cc] = -INFINITY;
        }
        float mx = fmaxf(fmaxf(sv[0],sv[1]), fmaxf(sv[2],sv[3]));
        mx = fmaxf(mx, __shfl_xor(mx,1));
        mx = fmaxf(mx, __shfl_xor(mx,2));
        mx = fmaxf(mx, __shfl_xor(mx,4));
        mx = fmaxf(mx, __shfl_xor(mx,8));
        float mn = fmaxf(mrow[rg], mx);
        float al = exp2f(mrow[rg] - mn);
        mrow[rg] = mn;
        float p0 = exp2f(sv[0]-mn), p1 = exp2f(sv[1]-mn);
        float p2 = exp2f(sv[2]-mn), p3 = exp2f(sv[3]-mn);
        float ps = (p0+p1)+(p2+p3);
        ps += __shfl_xor(ps,1); ps += __shfl_xor(ps,2);
        ps += __shfl_xor(ps,4); ps += __shfl_xor(ps,8);
        srow[rg] = srow[rg]*al + ps;
        alpha[rg] = al;
        const int r = g4*4+rg;
        const int rs = r*64, rx = r&7;
        float pv[4] = {p0,p1,p2,p3};
        #pragma unroll
        for (int cc=0;cc<4;cc++) {
          int c = cc*16+cl;
          Pw[rs + (((c>>3) ^ rx))*8 + (c&7)] = f2bf(pv[cc]);
        }
      }
      // ---- rescale O, PV from LDS ----
      #pragma unroll
      for (int dc=0;dc<8;dc++)
        #pragma unroll
        for (int rg=0;rg<4;rg++) O[dc][rg] *= alpha[rg];
      #pragma unroll
      for (int cc2=0;cc2<2;cc2++) {
        bf16x8 pf = *(const bf16x8*)&Pw[cl*64 + (((cc2*4+g4) ^ (cl&7)))*8];
        #pragma unroll
        for (int dc=0;dc<8;dc++) {
          bf16x8 vf = *(const bf16x8*)&Vtl[(dc*16+cl)*64 + (((cc2*4+g4) ^ (cl&7)))*8];
          O[dc] = __builtin_amdgcn_mfma_f32_16x16x32_bf16(pf, vf, O[dc], 0,0,0);
        }
      }
      __syncthreads();   // drains staged loads (compiler emits vmcnt(0)) + all waves done with cur
      cur ^= 1;
    }
    // ---- epilogue for this tile ----
    #pragma unroll
    for (int rg=0;rg<4;rg++) {
      float inv = 1.0f / srow[rg];
      size_t ob = ((size_t)b*SS + q0 + w*16 + g4*4 + rg)*4096 + (size_t)h*HD;
      #pragma unroll
      for (int dc=0;dc<8;dc++)
        out[ob + dc*16 + cl] = f2bf(O[dc][rg]*inv);
    }
  }
}

// ---------------- host launcher ----------------
extern "C" void kernel_launch(void* const* d_in, const int* in_sizes, int n_in,
                              void* d_out, int out_size, void* d_ws, size_t ws_size,
                              hipStream_t stream)
{
  const float* hid = (const float*)d_in[0];
  const int*   pos = (const int*)d_in[1];
  const float* wq  = (const float*)d_in[2];
  const float* wk  = (const float*)d_in[3];
  const float* wv  = (const float*)d_in[4];
  const float* wo  = (const float*)d_in[5];
  const float* qsc = (const float*)d_in[6];
  const float* ksc = (const float*)d_in[7];

  char* ws = (char*)d_ws;
  size_t off = 0;
  auto alloc = [&](size_t b) -> char* {
    char* p = ws + off;
    off = (off + b + 255) & ~(size_t)255;
    return p;
  };
  u16*    h_bf   = (u16*)   alloc((size_t)NTOK*HIDDEN*2);
  u16*    wqkv_t = (u16*)   alloc((size_t)NQKV*HIDDEN*2);
  u16*    wo_t   = (u16*)   alloc((size_t)HIDDEN*HIDDEN*2);
  u16*    qkv    = (u16*)   alloc((size_t)NTOK*NQKV*2);
  u16*    attn_o = (u16*)   alloc((size_t)NTOK*HIDDEN*2);
  u16*    vtb    = (u16*)   alloc((size_t)BB*NKV*HD*SS*2);
  float2* tab    = (float2*)alloc((size_t)NTOK*64*sizeof(float2));

  cast_f32_bf16_k<<<2048, 256, 0, stream>>>((const float4*)hid, (ushort4*)h_bf, NTOK*HIDDEN/8);
  transpose_cast64<<<dim3(HIDDEN/64, HIDDEN/64), 256, 0, stream>>>(wq, wqkv_t, HIDDEN, HIDDEN);
  transpose_cast64<<<dim3(1024/64,  HIDDEN/64), 256, 0, stream>>>(wk, wqkv_t + (size_t)4096*HIDDEN, HIDDEN, 1024);
  transpose_cast64<<<dim3(1024/64,  HIDDEN/64), 256, 0, stream>>>(wv, wqkv_t + (size_t)5120*HIDDEN, HIDDEN, 1024);
  transpose_cast64<<<dim3(HIDDEN/64, HIDDEN/64), 256, 0, stream>>>(wo, wo_t, HIDDEN, HIDDEN);
  rope_tab_k<<<NTOK*64/256, 256, 0, stream>>>(pos, tab);

  // QKV GEMM with fused RMSNorm+RoPE epilogue (n-tile == head)
  gemm_bt<2><<<dim3(NQKV/128, NTOK/128), 256, 0, stream>>>(h_bf, wqkv_t, qkv, NTOK, NQKV, HIDDEN, qsc, ksc, tab);
  v_transpose<<<dim3(SS/32, BB*NKV), 256, 0, stream>>>(qkv, vtb);
  attn_fwd<<<dim3(8, NQ, BB), 256, 0, stream>>>(qkv, vtb, attn_o);
  gemm_bt<0><<<dim3(HIDDEN/128, NTOK/128), 256, 0, stream>>>(attn_o, wo_t, d_out, NTOK, HIDDEN, HIDDEN, nullptr, nullptr, nullptr);
}